// Round 1
// baseline (57.780 us; speedup 1.0000x reference)
//
#include <hip/hip_runtime.h>
#include <hip/hip_bf16.h>

typedef __attribute__((ext_vector_type(8))) short bf16x8;
typedef __attribute__((ext_vector_type(4))) float f32x4;

#define NGRAPH   4096
#define NNODES   262144
#define LATENT   256
#define H2       512
#define HID      256
#define NF       128
#define GPB      16          // graphs per block
#define THREADS  512         // 8 waves

// padded LDS strides (row stride mod 32 banks == 4 -> 2-way, free)
#define ZS_S 264
#define HS_S 520
#define HD_S 264

static __device__ __forceinline__ short f2bf(float x) {
    union { float f; unsigned u; } c; c.f = x;
    unsigned r = c.u + 0x7fffu + ((c.u >> 16) & 1u);   // RTNE
    return (short)(r >> 16);
}

// ---------------------------------------------------------------------------
// prep: W (fp32, [K][N] row-major) -> W^T (bf16, [N][K] row-major) in d_ws
// ---------------------------------------------------------------------------
__global__ __launch_bounds__(256) void prep_kernel(
    const float* __restrict__ wlp, const float* __restrict__ w1,
    const float* __restrict__ w2,
    short* __restrict__ wlp_t, short* __restrict__ w1_t, short* __restrict__ w2_t)
{
    int i = blockIdx.x * 256 + threadIdx.x;
    if (i < LATENT * H2) {                       // wlp_t [512][256]
        int n = i >> 8, k = i & 255;
        wlp_t[i] = f2bf(wlp[k * H2 + n]);
    } else if (i < 2 * LATENT * H2) {            // w1_t [256][512]
        int j = i - LATENT * H2;
        int n = j >> 9, k = j & 511;
        w1_t[j] = f2bf(w1[k * HID + n]);
    } else if (i < 2 * LATENT * H2 + HID * NF) { // w2_t [128][256]
        int j = i - 2 * LATENT * H2;
        int n = j >> 8, k = j & 255;
        w2_t[j] = f2bf(w2[k * NF + n]);
    }
}

// ---------------------------------------------------------------------------
// fused: per-block 16-graph MLP (bf16 MFMA) + node gather-write
// ---------------------------------------------------------------------------
__global__ __launch_bounds__(THREADS) void fused_kernel(
    const float* __restrict__ z, const int* __restrict__ seg,
    const short* __restrict__ wlp_t, const short* __restrict__ w1_t,
    const short* __restrict__ w2_t,
    const float* __restrict__ b_lp, const float* __restrict__ b1,
    const float* __restrict__ b2,
    float* __restrict__ out)
{
    __shared__ short zs[GPB * ZS_S];   // z tile, bf16
    __shared__ short hs[GPB * HS_S];   // h  tile, bf16
    __shared__ short hd[GPB * HD_S];   // hid tile, bf16
    __shared__ float ou[GPB * NF];     // out_unique tile, fp32

    const int tid = threadIdx.x;
    const int w   = tid >> 6;          // wave 0..7
    const int l15 = tid & 15;
    const int lq  = (tid >> 4) & 3;
    const int gbase = blockIdx.x * GPB;

    // ---- stage z: 16x256 fp32 -> bf16 LDS (padded)
    {
        const float4* zsrc = (const float4*)(z + (size_t)gbase * LATENT);
        #pragma unroll
        for (int it = 0; it < (GPB * LATENT / 4) / THREADS; ++it) {
            int idx = tid + it * THREADS;       // float4 index, 0..1023
            int row = idx >> 6, c4 = idx & 63;
            float4 v = zsrc[idx];
            short4 s4;
            s4.x = f2bf(v.x); s4.y = f2bf(v.y); s4.z = f2bf(v.z); s4.w = f2bf(v.w);
            *(short4*)&zs[row * ZS_S + c4 * 4] = s4;
        }
    }
    __syncthreads();

    // ---- phase 1: h = relu(z @ Wlp + b_lp), [16 x 512], K=256
    {
        const int cb = w * 64;                  // wave's 64 output cols
        f32x4 acc[4];
        #pragma unroll
        for (int ct = 0; ct < 4; ++ct) acc[ct] = (f32x4){0.f, 0.f, 0.f, 0.f};
        #pragma unroll
        for (int ks = 0; ks < LATENT / 32; ++ks) {
            bf16x8 a = *(const bf16x8*)&zs[l15 * ZS_S + ks * 32 + lq * 8];
            #pragma unroll
            for (int ct = 0; ct < 4; ++ct) {
                bf16x8 b = *(const bf16x8*)&wlp_t[(cb + ct * 16 + l15) * LATENT + ks * 32 + lq * 8];
                acc[ct] = __builtin_amdgcn_mfma_f32_16x16x32_bf16(a, b, acc[ct], 0, 0, 0);
            }
        }
        #pragma unroll
        for (int ct = 0; ct < 4; ++ct) {
            const int col = cb + ct * 16 + l15;
            const float bias = b_lp[col];
            #pragma unroll
            for (int i = 0; i < 4; ++i) {
                float v = acc[ct][i] + bias;
                hs[(lq * 4 + i) * HS_S + col] = f2bf(fmaxf(v, 0.f));
            }
        }
    }
    __syncthreads();

    // ---- phase 2: hid = relu(h @ W1 + b1), [16 x 256], K=512
    {
        const int cb = w * 32;
        f32x4 acc[2];
        #pragma unroll
        for (int ct = 0; ct < 2; ++ct) acc[ct] = (f32x4){0.f, 0.f, 0.f, 0.f};
        #pragma unroll
        for (int ks = 0; ks < H2 / 32; ++ks) {
            bf16x8 a = *(const bf16x8*)&hs[l15 * HS_S + ks * 32 + lq * 8];
            #pragma unroll
            for (int ct = 0; ct < 2; ++ct) {
                bf16x8 b = *(const bf16x8*)&w1_t[(cb + ct * 16 + l15) * H2 + ks * 32 + lq * 8];
                acc[ct] = __builtin_amdgcn_mfma_f32_16x16x32_bf16(a, b, acc[ct], 0, 0, 0);
            }
        }
        #pragma unroll
        for (int ct = 0; ct < 2; ++ct) {
            const int col = cb + ct * 16 + l15;
            const float bias = b1[col];
            #pragma unroll
            for (int i = 0; i < 4; ++i) {
                float v = acc[ct][i] + bias;
                hd[(lq * 4 + i) * HD_S + col] = f2bf(fmaxf(v, 0.f));
            }
        }
    }
    __syncthreads();

    // ---- phase 3: out_u = hid @ W2 + b2, [16 x 128], K=256
    {
        const int cb = w * 16;
        f32x4 acc = (f32x4){0.f, 0.f, 0.f, 0.f};
        #pragma unroll
        for (int ks = 0; ks < HID / 32; ++ks) {
            bf16x8 a = *(const bf16x8*)&hd[l15 * HD_S + ks * 32 + lq * 8];
            bf16x8 b = *(const bf16x8*)&w2_t[(cb + l15) * HID + ks * 32 + lq * 8];
            acc = __builtin_amdgcn_mfma_f32_16x16x32_bf16(a, b, acc, 0, 0, 0);
        }
        const int col = cb + l15;
        const float bias = b2[col];
        #pragma unroll
        for (int i = 0; i < 4; ++i)
            ou[(lq * 4 + i) * NF + col] = acc[i] + bias;
    }
    __syncthreads();

    // ---- gather-write: nodes whose segment is in [gbase, gbase+GPB)
    int lo, hi;
    {
        int a = 0, b = NNODES;                       // lower_bound(gbase)
        while (a < b) { int m = (a + b) >> 1; if (seg[m] < gbase) a = m + 1; else b = m; }
        lo = a;
        int a2 = lo, b2 = NNODES;                    // lower_bound(gbase+GPB)
        while (a2 < b2) { int m = (a2 + b2) >> 1; if (seg[m] < gbase + GPB) a2 = m + 1; else b2 = m; }
        hi = a2;
    }
    const int total4 = (hi - lo) * (NF / 4);
    for (int idx = tid; idx < total4; idx += THREADS) {
        int node = lo + (idx >> 5);
        int f4 = idx & 31;
        int g = seg[node] - gbase;
        float4 v = *(const float4*)&ou[g * NF + f4 * 4];
        *(float4*)&out[(size_t)node * NF + (size_t)f4 * 4] = v;
    }
}

// ---------------------------------------------------------------------------
extern "C" void kernel_launch(void* const* d_in, const int* in_sizes, int n_in,
                              void* d_out, int out_size, void* d_ws, size_t ws_size,
                              hipStream_t stream) {
    const float* z    = (const float*)d_in[0];
    const int*   seg  = (const int*)  d_in[1];
    const float* wlp  = (const float*)d_in[2];
    const float* b_lp = (const float*)d_in[3];
    const float* w1   = (const float*)d_in[4];
    const float* b1   = (const float*)d_in[5];
    const float* w2   = (const float*)d_in[6];
    const float* b2   = (const float*)d_in[7];
    float* out = (float*)d_out;

    short* wlp_t = (short*)d_ws;                 // [512][256] bf16
    short* w1_t  = wlp_t + LATENT * H2;          // [256][512] bf16
    short* w2_t  = w1_t + H2 * HID;              // [128][256] bf16

    const int prep_elems = 2 * LATENT * H2 + HID * NF;   // 294912
    prep_kernel<<<prep_elems / 256, 256, 0, stream>>>(wlp, w1, w2, wlp_t, w1_t, w2_t);
    fused_kernel<<<NGRAPH / GPB, THREADS, 0, stream>>>(z, seg, wlp_t, w1_t, w2_t,
                                                       b_lp, b1, b2, out);
}

// Round 2
// 55.751 us; speedup vs baseline: 1.0364x; 1.0364x over previous
//
#include <hip/hip_runtime.h>
#include <hip/hip_bf16.h>

typedef __attribute__((ext_vector_type(8))) short bf16x8;
typedef __attribute__((ext_vector_type(4))) float f32x4;

#define NGRAPH   4096
#define NNODES   262144
#define LATENT   256
#define H2       512
#define HID      256
#define NF       128

#define GPB      32            // graphs per block (kernel A)
#define ATHREADS 512           // 8 waves
#define ABLOCKS  (NGRAPH / GPB)            // 128

#define BTHREADS 256
#define BBLOCKS  2048
#define BITERS   ((NNODES * (NF / 4)) / (BBLOCKS * BTHREADS))   // 16

// padded LDS strides (row stride mod 32 banks == 4 -> 2-way, free)
#define ZS_S 264
#define HS_S 520
#define HD_S 264

static __device__ __forceinline__ short f2bf(float x) {
    union { float f; unsigned u; } c; c.f = x;
    unsigned r = c.u + 0x7fffu + ((c.u >> 16) & 1u);   // RTNE
    return (short)(r >> 16);
}

// ---------------------------------------------------------------------------
// prep: W (fp32, [K][N] row-major) -> W^T (bf16, [N][K] row-major) in d_ws
// ---------------------------------------------------------------------------
__global__ __launch_bounds__(256) void prep_kernel(
    const float* __restrict__ wlp, const float* __restrict__ w1,
    const float* __restrict__ w2,
    short* __restrict__ wlp_t, short* __restrict__ w1_t, short* __restrict__ w2_t)
{
    int i = blockIdx.x * 256 + threadIdx.x;
    if (i < LATENT * H2) {                       // wlp_t [512][256]
        int n = i >> 8, k = i & 255;
        wlp_t[i] = f2bf(wlp[k * H2 + n]);
    } else if (i < 2 * LATENT * H2) {            // w1_t [256][512]
        int j = i - LATENT * H2;
        int n = j >> 9, k = j & 511;
        w1_t[j] = f2bf(w1[k * HID + n]);
    } else if (i < 2 * LATENT * H2 + HID * NF) { // w2_t [128][256]
        int j = i - 2 * LATENT * H2;
        int n = j >> 8, k = j & 255;
        w2_t[j] = f2bf(w2[k * NF + n]);
    }
}

// ---------------------------------------------------------------------------
// kernel A: 3-layer MLP on the 4096 unique graphs -> ou [4096][128] fp32 (ws)
// ---------------------------------------------------------------------------
__global__ __launch_bounds__(ATHREADS) void mlp_kernel(
    const float* __restrict__ z,
    const short* __restrict__ wlp_t, const short* __restrict__ w1_t,
    const short* __restrict__ w2_t,
    const float* __restrict__ b_lp, const float* __restrict__ b1,
    const float* __restrict__ b2,
    float* __restrict__ ou)
{
    __shared__ short zs[GPB * ZS_S];   // z tile, bf16
    __shared__ short hs[GPB * HS_S];   // h  tile, bf16
    __shared__ short hd[GPB * HD_S];   // hid tile, bf16
    __shared__ float ous[GPB * NF];    // out tile, fp32

    const int tid = threadIdx.x;
    const int w   = tid >> 6;          // wave 0..7
    const int l15 = tid & 15;
    const int lq  = (tid >> 4) & 3;
    const int gbase = blockIdx.x * GPB;

    // ---- stage z: 32x256 fp32 -> bf16 LDS (padded)
    {
        const float4* zsrc = (const float4*)(z + (size_t)gbase * LATENT);
        #pragma unroll
        for (int it = 0; it < (GPB * LATENT / 4) / ATHREADS; ++it) {
            int idx = tid + it * ATHREADS;      // float4 index
            int row = idx >> 6, c4 = idx & 63;
            float4 v = zsrc[idx];
            short4 s4;
            s4.x = f2bf(v.x); s4.y = f2bf(v.y); s4.z = f2bf(v.z); s4.w = f2bf(v.w);
            *(short4*)&zs[row * ZS_S + c4 * 4] = s4;
        }
    }
    __syncthreads();

    // ---- phase 1: h = relu(z @ Wlp + b_lp), [32 x 512], K=256
    {
        const int cb = w * 64;
        f32x4 acc[2][4];
        #pragma unroll
        for (int rt = 0; rt < 2; ++rt)
            #pragma unroll
            for (int ct = 0; ct < 4; ++ct) acc[rt][ct] = (f32x4){0.f, 0.f, 0.f, 0.f};
        #pragma unroll
        for (int ks = 0; ks < LATENT / 32; ++ks) {
            bf16x8 a0 = *(const bf16x8*)&zs[l15 * ZS_S + ks * 32 + lq * 8];
            bf16x8 a1 = *(const bf16x8*)&zs[(16 + l15) * ZS_S + ks * 32 + lq * 8];
            #pragma unroll
            for (int ct = 0; ct < 4; ++ct) {
                bf16x8 b = *(const bf16x8*)&wlp_t[(cb + ct * 16 + l15) * LATENT + ks * 32 + lq * 8];
                acc[0][ct] = __builtin_amdgcn_mfma_f32_16x16x32_bf16(a0, b, acc[0][ct], 0, 0, 0);
                acc[1][ct] = __builtin_amdgcn_mfma_f32_16x16x32_bf16(a1, b, acc[1][ct], 0, 0, 0);
            }
        }
        #pragma unroll
        for (int ct = 0; ct < 4; ++ct) {
            const int col = cb + ct * 16 + l15;
            const float bias = b_lp[col];
            #pragma unroll
            for (int rt = 0; rt < 2; ++rt)
                #pragma unroll
                for (int i = 0; i < 4; ++i) {
                    float v = acc[rt][ct][i] + bias;
                    hs[(rt * 16 + lq * 4 + i) * HS_S + col] = f2bf(fmaxf(v, 0.f));
                }
        }
    }
    __syncthreads();

    // ---- phase 2: hid = relu(h @ W1 + b1), [32 x 256], K=512
    {
        const int cb = w * 32;
        f32x4 acc[2][2];
        #pragma unroll
        for (int rt = 0; rt < 2; ++rt)
            #pragma unroll
            for (int ct = 0; ct < 2; ++ct) acc[rt][ct] = (f32x4){0.f, 0.f, 0.f, 0.f};
        #pragma unroll
        for (int ks = 0; ks < H2 / 32; ++ks) {
            bf16x8 a0 = *(const bf16x8*)&hs[l15 * HS_S + ks * 32 + lq * 8];
            bf16x8 a1 = *(const bf16x8*)&hs[(16 + l15) * HS_S + ks * 32 + lq * 8];
            #pragma unroll
            for (int ct = 0; ct < 2; ++ct) {
                bf16x8 b = *(const bf16x8*)&w1_t[(cb + ct * 16 + l15) * H2 + ks * 32 + lq * 8];
                acc[0][ct] = __builtin_amdgcn_mfma_f32_16x16x32_bf16(a0, b, acc[0][ct], 0, 0, 0);
                acc[1][ct] = __builtin_amdgcn_mfma_f32_16x16x32_bf16(a1, b, acc[1][ct], 0, 0, 0);
            }
        }
        #pragma unroll
        for (int ct = 0; ct < 2; ++ct) {
            const int col = cb + ct * 16 + l15;
            const float bias = b1[col];
            #pragma unroll
            for (int rt = 0; rt < 2; ++rt)
                #pragma unroll
                for (int i = 0; i < 4; ++i) {
                    float v = acc[rt][ct][i] + bias;
                    hd[(rt * 16 + lq * 4 + i) * HD_S + col] = f2bf(fmaxf(v, 0.f));
                }
        }
    }
    __syncthreads();

    // ---- phase 3: out_u = hid @ W2 + b2, [32 x 128], K=256
    {
        const int cb = w * 16;
        f32x4 acc[2];
        acc[0] = (f32x4){0.f, 0.f, 0.f, 0.f};
        acc[1] = (f32x4){0.f, 0.f, 0.f, 0.f};
        #pragma unroll
        for (int ks = 0; ks < HID / 32; ++ks) {
            bf16x8 a0 = *(const bf16x8*)&hd[l15 * HD_S + ks * 32 + lq * 8];
            bf16x8 a1 = *(const bf16x8*)&hd[(16 + l15) * HD_S + ks * 32 + lq * 8];
            bf16x8 b = *(const bf16x8*)&w2_t[(cb + l15) * HID + ks * 32 + lq * 8];
            acc[0] = __builtin_amdgcn_mfma_f32_16x16x32_bf16(a0, b, acc[0], 0, 0, 0);
            acc[1] = __builtin_amdgcn_mfma_f32_16x16x32_bf16(a1, b, acc[1], 0, 0, 0);
        }
        const int col = cb + l15;
        const float bias = b2[col];
        #pragma unroll
        for (int rt = 0; rt < 2; ++rt)
            #pragma unroll
            for (int i = 0; i < 4; ++i)
                ous[(rt * 16 + lq * 4 + i) * NF + col] = acc[rt][i] + bias;
    }
    __syncthreads();

    // ---- coalesced write of the 32x128 fp32 tile to global ws
    {
        float4* dst = (float4*)(ou + (size_t)gbase * NF);
        const float4* src = (const float4*)ous;
        #pragma unroll
        for (int it = 0; it < (GPB * NF / 4) / ATHREADS; ++it)
            dst[tid + it * ATHREADS] = src[tid + it * ATHREADS];
    }
}

// ---------------------------------------------------------------------------
// kernel B: broadcast-scatter  out[node] = ou[seg[node]]  (pure write stream)
// ---------------------------------------------------------------------------
__global__ __launch_bounds__(BTHREADS) void scatter_kernel(
    const int* __restrict__ seg, const float* __restrict__ ou,
    float* __restrict__ out)
{
    const int t = blockIdx.x * BTHREADS + threadIdx.x;
    const float4* ou4 = (const float4*)ou;
    float4* out4 = (float4*)out;
    #pragma unroll 4
    for (int it = 0; it < BITERS; ++it) {
        int idx = t + it * (BBLOCKS * BTHREADS);
        int node = idx >> 5;            // NF/4 = 32 float4 per node
        int f4 = idx & 31;
        int g = seg[node];
        out4[idx] = ou4[g * (NF / 4) + f4];
    }
}

// ---------------------------------------------------------------------------
extern "C" void kernel_launch(void* const* d_in, const int* in_sizes, int n_in,
                              void* d_out, int out_size, void* d_ws, size_t ws_size,
                              hipStream_t stream) {
    const float* z    = (const float*)d_in[0];
    const int*   seg  = (const int*)  d_in[1];
    const float* wlp  = (const float*)d_in[2];
    const float* b_lp = (const float*)d_in[3];
    const float* w1   = (const float*)d_in[4];
    const float* b1   = (const float*)d_in[5];
    const float* w2   = (const float*)d_in[6];
    const float* b2   = (const float*)d_in[7];
    float* out = (float*)d_out;

    short* wlp_t = (short*)d_ws;                 // [512][256] bf16
    short* w1_t  = wlp_t + LATENT * H2;          // [256][512] bf16
    short* w2_t  = w1_t + H2 * HID;              // [128][256] bf16
    float* ou    = (float*)(w2_t + HID * NF);    // [4096][128] fp32 (16B aligned)

    const int prep_elems = 2 * LATENT * H2 + HID * NF;   // 294912
    prep_kernel<<<prep_elems / 256, 256, 0, stream>>>(wlp, w1, w2, wlp_t, w1_t, w2_t);
    mlp_kernel<<<ABLOCKS, ATHREADS, 0, stream>>>(z, wlp_t, w1_t, w2_t, b_lp, b1, b2, ou);
    scatter_kernel<<<BBLOCKS, BTHREADS, 0, stream>>>(seg, ou, out);
}

// Round 3
// 51.981 us; speedup vs baseline: 1.1116x; 1.0725x over previous
//
#include <hip/hip_runtime.h>
#include <hip/hip_bf16.h>

typedef __attribute__((ext_vector_type(8))) short bf16x8;
typedef __attribute__((ext_vector_type(4))) float f32x4;

#define NGRAPH   4096
#define NNODES   262144
#define LATENT   256
#define H2       512
#define HID      256
#define NF       128

#define GPB      16            // graphs per block (kernel A)
#define ATHREADS 512           // 8 waves
#define ABLOCKS  (NGRAPH / GPB)            // 256

#define STHREADS 256           // 4 waves
#define NODES_PER_WAVE 64
#define SBLOCKS  (NNODES / (NODES_PER_WAVE * 4))   // 1024

// padded LDS strides (row stride mod 32 banks == 4 -> 2-way, free)
#define ZS_S 264
#define HS_S 520
#define HD_S 264

static __device__ __forceinline__ short f2bf(float x) {
    union { float f; unsigned u; } c; c.f = x;
    unsigned r = c.u + 0x7fffu + ((c.u >> 16) & 1u);   // RTNE
    return (short)(r >> 16);
}

// ---------------------------------------------------------------------------
// prep: W (fp32, [K][N] row-major) -> W^T (bf16, [N][K] row-major) in d_ws
// ---------------------------------------------------------------------------
__global__ __launch_bounds__(256) void prep_kernel(
    const float* __restrict__ wlp, const float* __restrict__ w1,
    const float* __restrict__ w2,
    short* __restrict__ wlp_t, short* __restrict__ w1_t, short* __restrict__ w2_t)
{
    int i = blockIdx.x * 256 + threadIdx.x;
    if (i < LATENT * H2) {                       // wlp_t [512][256]
        int n = i >> 8, k = i & 255;
        wlp_t[i] = f2bf(wlp[k * H2 + n]);
    } else if (i < 2 * LATENT * H2) {            // w1_t [256][512]
        int j = i - LATENT * H2;
        int n = j >> 9, k = j & 511;
        w1_t[j] = f2bf(w1[k * HID + n]);
    } else if (i < 2 * LATENT * H2 + HID * NF) { // w2_t [128][256]
        int j = i - 2 * LATENT * H2;
        int n = j >> 8, k = j & 255;
        w2_t[j] = f2bf(w2[k * NF + n]);
    }
}

// ---------------------------------------------------------------------------
// kernel A: 3-layer MLP on the 4096 unique graphs -> ou [4096][128] fp32 (ws)
// ---------------------------------------------------------------------------
__global__ __launch_bounds__(ATHREADS) void mlp_kernel(
    const float* __restrict__ z,
    const short* __restrict__ wlp_t, const short* __restrict__ w1_t,
    const short* __restrict__ w2_t,
    const float* __restrict__ b_lp, const float* __restrict__ b1,
    const float* __restrict__ b2,
    float* __restrict__ ou)
{
    __shared__ short zs[GPB * ZS_S];   // z tile, bf16
    __shared__ short hs[GPB * HS_S];   // h  tile, bf16
    __shared__ short hd[GPB * HD_S];   // hid tile, bf16
    __shared__ float ous[GPB * NF];    // out tile, fp32

    const int tid = threadIdx.x;
    const int w   = tid >> 6;          // wave 0..7
    const int l15 = tid & 15;
    const int lq  = (tid >> 4) & 3;
    const int gbase = blockIdx.x * GPB;

    // ---- stage z: 16x256 fp32 -> bf16 LDS (padded)
    {
        const float4* zsrc = (const float4*)(z + (size_t)gbase * LATENT);
        #pragma unroll
        for (int it = 0; it < (GPB * LATENT / 4) / ATHREADS; ++it) {
            int idx = tid + it * ATHREADS;      // float4 index
            int row = idx >> 6, c4 = idx & 63;
            float4 v = zsrc[idx];
            short4 s4;
            s4.x = f2bf(v.x); s4.y = f2bf(v.y); s4.z = f2bf(v.z); s4.w = f2bf(v.w);
            *(short4*)&zs[row * ZS_S + c4 * 4] = s4;
        }
    }
    __syncthreads();

    // ---- phase 1: h = relu(z @ Wlp + b_lp), [16 x 512], K=256
    {
        const int cb = w * 64;                  // wave's 64 output cols
        f32x4 acc[4];
        #pragma unroll
        for (int ct = 0; ct < 4; ++ct) acc[ct] = (f32x4){0.f, 0.f, 0.f, 0.f};
        #pragma unroll
        for (int ks = 0; ks < LATENT / 32; ++ks) {
            bf16x8 a = *(const bf16x8*)&zs[l15 * ZS_S + ks * 32 + lq * 8];
            #pragma unroll
            for (int ct = 0; ct < 4; ++ct) {
                bf16x8 b = *(const bf16x8*)&wlp_t[(cb + ct * 16 + l15) * LATENT + ks * 32 + lq * 8];
                acc[ct] = __builtin_amdgcn_mfma_f32_16x16x32_bf16(a, b, acc[ct], 0, 0, 0);
            }
        }
        #pragma unroll
        for (int ct = 0; ct < 4; ++ct) {
            const int col = cb + ct * 16 + l15;
            const float bias = b_lp[col];
            #pragma unroll
            for (int i = 0; i < 4; ++i) {
                float v = acc[ct][i] + bias;
                hs[(lq * 4 + i) * HS_S + col] = f2bf(fmaxf(v, 0.f));
            }
        }
    }
    __syncthreads();

    // ---- phase 2: hid = relu(h @ W1 + b1), [16 x 256], K=512
    {
        const int cb = w * 32;
        f32x4 acc[2];
        #pragma unroll
        for (int ct = 0; ct < 2; ++ct) acc[ct] = (f32x4){0.f, 0.f, 0.f, 0.f};
        #pragma unroll
        for (int ks = 0; ks < H2 / 32; ++ks) {
            bf16x8 a = *(const bf16x8*)&hs[l15 * HS_S + ks * 32 + lq * 8];
            #pragma unroll
            for (int ct = 0; ct < 2; ++ct) {
                bf16x8 b = *(const bf16x8*)&w1_t[(cb + ct * 16 + l15) * H2 + ks * 32 + lq * 8];
                acc[ct] = __builtin_amdgcn_mfma_f32_16x16x32_bf16(a, b, acc[ct], 0, 0, 0);
            }
        }
        #pragma unroll
        for (int ct = 0; ct < 2; ++ct) {
            const int col = cb + ct * 16 + l15;
            const float bias = b1[col];
            #pragma unroll
            for (int i = 0; i < 4; ++i) {
                float v = acc[ct][i] + bias;
                hd[(lq * 4 + i) * HD_S + col] = f2bf(fmaxf(v, 0.f));
            }
        }
    }
    __syncthreads();

    // ---- phase 3: out_u = hid @ W2 + b2, [16 x 128], K=256
    {
        const int cb = w * 16;
        f32x4 acc = (f32x4){0.f, 0.f, 0.f, 0.f};
        #pragma unroll
        for (int ks = 0; ks < HID / 32; ++ks) {
            bf16x8 a = *(const bf16x8*)&hd[l15 * HD_S + ks * 32 + lq * 8];
            bf16x8 b = *(const bf16x8*)&w2_t[(cb + l15) * HID + ks * 32 + lq * 8];
            acc = __builtin_amdgcn_mfma_f32_16x16x32_bf16(a, b, acc, 0, 0, 0);
        }
        const int col = cb + l15;
        const float bias = b2[col];
        #pragma unroll
        for (int i = 0; i < 4; ++i)
            ous[(lq * 4 + i) * NF + col] = acc[i] + bias;
    }
    __syncthreads();

    // ---- coalesced write of the 16x128 fp32 tile to global ws
    {
        float4* dst = (float4*)(ou + (size_t)gbase * NF);
        const float4* src = (const float4*)ous;
        dst[tid] = src[tid];           // 512 float4 = 512 threads, 1 each
    }
}

// ---------------------------------------------------------------------------
// kernel B: broadcast-scatter  out[node] = ou[seg[node]]
// 1 wave = 64 consecutive nodes; row register-cached, reload only on g-change.
// ---------------------------------------------------------------------------
__global__ __launch_bounds__(STHREADS) void scatter_kernel(
    const int* __restrict__ seg, const float* __restrict__ ou,
    float* __restrict__ out)
{
    const int tid  = threadIdx.x;
    const int lane = tid & 63;
    const int half = lane >> 5;            // 0: even node, 1: odd node
    const int f4   = lane & 31;            // float4 slot within the row
    const int gw   = blockIdx.x * (STHREADS / 64) + (tid >> 6);  // global wave
    const int nbase = gw * NODES_PER_WAVE;

    const float4* ou4 = (const float4*)ou;
    float4* out4 = (float4*)out;

    // preload this wave's 64 seg values (one per lane)
    int s_n = seg[nbase + lane];

    f32x4 v;
    int gcache = -1;
    #pragma unroll 4
    for (int i = 0; i < NODES_PER_WAVE / 2; ++i) {
        int g = __shfl(s_n, 2 * i + half);     // lanes 0-31: node 2i, 32-63: 2i+1
        if (__any(g != gcache)) {
            v = *(const f32x4*)&ou4[(size_t)g * (NF / 4) + f4];
            gcache = g;
        }
        int n = nbase + 2 * i;                 // lanes store [n*512B, n*512B+1KB)
        *(f32x4*)&out4[(size_t)n * (NF / 4) + half * (NF / 4) + f4] = v;
    }
}

// ---------------------------------------------------------------------------
extern "C" void kernel_launch(void* const* d_in, const int* in_sizes, int n_in,
                              void* d_out, int out_size, void* d_ws, size_t ws_size,
                              hipStream_t stream) {
    const float* z    = (const float*)d_in[0];
    const int*   seg  = (const int*)  d_in[1];
    const float* wlp  = (const float*)d_in[2];
    const float* b_lp = (const float*)d_in[3];
    const float* w1   = (const float*)d_in[4];
    const float* b1   = (const float*)d_in[5];
    const float* w2   = (const float*)d_in[6];
    const float* b2   = (const float*)d_in[7];
    float* out = (float*)d_out;

    short* wlp_t = (short*)d_ws;                 // [512][256] bf16
    short* w1_t  = wlp_t + LATENT * H2;          // [256][512] bf16
    short* w2_t  = w1_t + H2 * HID;              // [128][256] bf16
    float* ou    = (float*)(w2_t + HID * NF);    // [4096][128] fp32 (16B aligned)

    const int prep_elems = 2 * LATENT * H2 + HID * NF;   // 294912
    prep_kernel<<<prep_elems / 256, 256, 0, stream>>>(wlp, w1, w2, wlp_t, w1_t, w2_t);
    mlp_kernel<<<ABLOCKS, ATHREADS, 0, stream>>>(z, wlp_t, w1_t, w2_t, b_lp, b1, b2, ou);
    scatter_kernel<<<SBLOCKS, STHREADS, 0, stream>>>(seg, ou, out);
}